// Round 13
// baseline (237.667 us; speedup 1.0000x reference)
//
#include <hip/hip_runtime.h>

// ---------------------------------------------------------------------------
// QuantizedLinear: y = x @ ((q - zp)*s)^T + bias    — INT8 MFMA path.
// Per-row x quant: s_x[m] = max|x[m,:]|/127, xq = rint(x/s_x)  (s8)
// Weight: qs8 = q - 128 (exact).  EXACT given quantized x:
//   y[m,o] = s_x[m]*s[o]*( G8[m,o] + (128-zp[o])*rq[m] ) + bias[o]
// Round 13: R12 structure (BM=256 BN=128 BK=64, 4-wave blocks, 48 KiB LDS,
// 2 blocks/CU) + R8's fragment-contiguous LDS layout replacing the broken
// 4-slot XOR swizzle (R12 PMC: 13.1M conflicts — 64-B rows have 16-bank
// stride, 4-way conflict at fixed read-group; provable, not fixable by
// 4-slot XOR). Fragment-contiguous: lane l stages (row l&15, kslot l>>4),
// so each 1 KiB chunk IS fragment order; ds_read = chunk + fr*16 + g*256
// -> 64 lanes span contiguous 1 KiB = 2 lanes/bank = free. Zero swizzle.
// Ledger (per-wave GLDS: A(t+1)[4 @ t-1 p1], B(t+1)[2 @ t p0],
// A(t+2)[4 @ t p1] = 10 outstanding at tile end):
//  p0: read a0-7,b0-1 |fence| b2-3 | stage B(t+1) | lgkm(2) | q0 m0-7 x n0-1
//  p1: lgkm(0) | B2 (WAR: buf-d reads done) | stage A(t+2) | q1 m0-7 x n2-3
//  end: vmcnt(4) steady / vmcnt(0) t>=NT-2 | B3 (RAW: t+1 landed)
// ---------------------------------------------------------------------------

typedef unsigned char u8;
typedef signed char s8;
typedef __attribute__((ext_vector_type(4))) int i32x4;
typedef __attribute__((ext_vector_type(4))) float f32x4;

#define M_TOK 8192
#define KDIM 4096
#define NDIM 4096
#define NT (KDIM / 64)  // 64 K-tiles of 64 i8

// --- helpers ---------------------------------------------------------------

__device__ __forceinline__ int pack4(int a, int b, int c, int d) {
  return (a & 255) | ((b & 255) << 8) | ((c & 255) << 16) |
         (int)(((unsigned)(d & 255)) << 24);
}

#define GLDS(gptr, lptr)                                                      \
  __builtin_amdgcn_global_load_lds(                                          \
      (const __attribute__((address_space(1))) void*)(gptr),                 \
      (__attribute__((address_space(3))) void*)(lptr), 16, 0, 0)

// --- kernel 1: x f32 -> s8 per-row quant, fused row max + row sum ----------

__global__ __launch_bounds__(256) void convert_x_kernel(
    const float* __restrict__ x, s8* __restrict__ xq,
    float* __restrict__ sx, float* __restrict__ rq) {
  const int row = blockIdx.x;
  const int tid = threadIdx.x;
  const float* xr = x + (size_t)row * KDIM + tid * 16;
  float4 v[4];
#pragma unroll
  for (int i = 0; i < 4; ++i) v[i] = ((const float4*)xr)[i];

  float mx = 0.f;
#pragma unroll
  for (int i = 0; i < 4; ++i) {
    mx = fmaxf(mx, fabsf(v[i].x)); mx = fmaxf(mx, fabsf(v[i].y));
    mx = fmaxf(mx, fabsf(v[i].z)); mx = fmaxf(mx, fabsf(v[i].w));
  }
#pragma unroll
  for (int off = 32; off > 0; off >>= 1)
    mx = fmaxf(mx, __shfl_down(mx, off, 64));
  __shared__ float redf[4];
  __shared__ float bmax;
  if ((tid & 63) == 0) redf[tid >> 6] = mx;
  __syncthreads();
  if (tid == 0)
    bmax = fmaxf(fmaxf(redf[0], redf[1]), fmaxf(redf[2], redf[3]));
  __syncthreads();
  const float maxv = bmax;
  const float inv = 127.0f / fmaxf(maxv, 1e-30f);

  int q[16];
  int ssum = 0;
#pragma unroll
  for (int i = 0; i < 4; ++i) {
    q[i * 4 + 0] = (int)rintf(v[i].x * inv);
    q[i * 4 + 1] = (int)rintf(v[i].y * inv);
    q[i * 4 + 2] = (int)rintf(v[i].z * inv);
    q[i * 4 + 3] = (int)rintf(v[i].w * inv);
  }
#pragma unroll
  for (int i = 0; i < 16; ++i) ssum += q[i];

  int4 o;
  o.x = pack4(q[0], q[1], q[2], q[3]);
  o.y = pack4(q[4], q[5], q[6], q[7]);
  o.z = pack4(q[8], q[9], q[10], q[11]);
  o.w = pack4(q[12], q[13], q[14], q[15]);
  *(int4*)(xq + (size_t)row * KDIM + tid * 16) = o;

#pragma unroll
  for (int off = 32; off > 0; off >>= 1) ssum += __shfl_down(ssum, off, 64);
  __shared__ int redi[4];
  if ((tid & 63) == 0) redi[tid >> 6] = ssum;
  __syncthreads();
  if (tid == 0) {
    sx[row] = maxv * (1.0f / 127.0f);
    rq[row] = (float)(redi[0] + redi[1] + redi[2] + redi[3]);  // < 2^24 exact
  }
}

// --- kernel 2: w int32 -> s8 (q - 128, exact) --------------------------------

__global__ __launch_bounds__(256) void convert_w_kernel(
    const int* __restrict__ wq, s8* __restrict__ wb) {
  const size_t idx = (size_t)blockIdx.x * 256 + threadIdx.x;  // 16 elems each
  const int4* src = (const int4*)wq + idx * 4;
  const int4 a = src[0], b = src[1], c = src[2], d = src[3];
  int4 o;
  o.x = pack4(a.x - 128, a.y - 128, a.z - 128, a.w - 128);
  o.y = pack4(b.x - 128, b.y - 128, b.z - 128, b.w - 128);
  o.z = pack4(c.x - 128, c.y - 128, c.z - 128, c.w - 128);
  o.w = pack4(d.x - 128, d.y - 128, d.z - 128, d.w - 128);
  ((int4*)wb)[idx] = o;
}

// --- kernel 3: 256x128 i8 GEMM, BK=64, 4 waves, 2 blocks/CU -----------------
// LDS chunks of 1 KiB = 16 rows x 64 B in FRAGMENT order:
// phys16B p (0..63) <-> (row = p&15, kslot = p>>4).

__global__ __launch_bounds__(256, 2) void qlin_gemm_kernel(
    const u8* __restrict__ A,         // [M][K] s8 bits
    const u8* __restrict__ B,         // [N][K] s8 bits
    const float* __restrict__ sx,     // [M]
    const float* __restrict__ rq,     // [M]
    const float* __restrict__ scale,  // [N]
    const float* __restrict__ zp,     // [N]
    const float* __restrict__ bias,   // [N]
    float* __restrict__ out) {        // [M][N]
  extern __shared__ u8 lds[];
  u8* Al = lds;           // [2][16 chunks][1024] = 32 KiB
  u8* Bl = lds + 32768;   // [2][ 8 chunks][1024] = 16 KiB

  const int tid = threadIdx.x;
  const int lane = tid & 63;
  const int wave = tid >> 6;  // 0..3
  const int wm = wave >> 1;   // 0..1  (128-row half)
  const int wn = wave & 1;    // 0..1  (64-col half)

  // T1: bijective XCD swizzle (1024 wgs, 1024%8==0)
  const int bid = blockIdx.x;
  const int swz = (bid & 7) * 128 + (bid >> 3);
  const int bm = swz >> 5;    // 0..31
  const int bn = swz & 31;    // 0..31
  const int row0 = bm * 256, col0 = bn * 128;

  const int fr = lane & 15;   // fragment row
  const int g = lane >> 4;    // k-slot group
  // staging: lane l fetches (row base+fr, k g*16..+15); GLDS dest is
  // wave-uniform chunk base + l*16 -> fragment-contiguous by construction.
  const u8* Ags = A + (size_t)(row0 + wave * 64 + fr) * KDIM + g * 16;
  const u8* Bgs = B + (size_t)(col0 + wave * 32 + fr) * KDIM + g * 16;
  u8* AldW = Al + wave * 4096;  // 4 chunks (rows wave*64 .. +63)
  u8* BldW = Bl + wave * 2048;  // 2 chunks (rows wave*32 .. +31)

#define STAGE_A(d, tau)                                                       \
  do {                                                                        \
    _Pragma("unroll") for (int i = 0; i < 4; ++i)                             \
        GLDS(Ags + (size_t)i * 16 * KDIM + (size_t)(tau) * 64,               \
             AldW + (d) * 16384 + i * 1024);                                 \
  } while (0)

#define STAGE_B(d, tau)                                                       \
  do {                                                                        \
    _Pragma("unroll") for (int j = 0; j < 2; ++j)                             \
        GLDS(Bgs + (size_t)j * 16 * KDIM + (size_t)(tau) * 64,               \
             BldW + (d) * 8192 + j * 1024);                                  \
  } while (0)

  // fragment reads: A chunk (wm*8+m), B chunk (wn*4+n); within-chunk offset
  // fr*16 + g*256 -> wave's 64 lanes span a contiguous 1 KiB (conflict-free).
  const u8* Ar = Al + wm * 8192 + fr * 16 + g * 256;
  const u8* Br = Bl + wn * 4096 + fr * 16 + g * 256;

#define LDA(d, m) (*(const i32x4*)(Ar + (d) * 16384 + (m) * 1024))
#define LDB(d, n) (*(const i32x4*)(Br + (d) * 8192 + (n) * 1024))
#define MFMA(d, va, vb) \
  d = __builtin_amdgcn_mfma_i32_16x16x64_i8(va, vb, d, 0, 0, 0)

  i32x4 acc[8][4] = {};
  i32x4 a[8], b[4];

  // prologue: A(0) 4, B(0) 2, A(1) 4 = 10 GLDS; vmcnt(4) -> tile0 landed,
  // A(1)'s 4 in flight.
  STAGE_A(0, 0);
  STAGE_B(0, 0);
  STAGE_A(1, 1);
  asm volatile("s_waitcnt vmcnt(4)" ::: "memory");
  __builtin_amdgcn_s_barrier();

  for (int t = 0; t < NT; ++t) {
    const int d = t & 1;

    // ---- p0: read a0-7, b0-1 | fence | b2-3 | stage B(t+1) | lgkm(2) |
    //      q0: m0-7 x n0-1 ----
#pragma unroll
    for (int m = 0; m < 8; ++m) a[m] = LDA(d, m);
    b[0] = LDB(d, 0); b[1] = LDB(d, 1);
    asm volatile("" ::: "memory");  // pin {a0-7,b0-1} before {b2-3}
    b[2] = LDB(d, 2); b[3] = LDB(d, 3);
    if (t + 1 < NT) STAGE_B(d ^ 1, t + 1);
    asm volatile("s_waitcnt lgkmcnt(2)" ::: "memory");  // a0-7 + b0-1 ready
    __builtin_amdgcn_s_setprio(1);
#pragma unroll
    for (int m = 0; m < 8; ++m)
#pragma unroll
      for (int n = 0; n < 2; ++n) MFMA(acc[m][n], a[m], b[n]);
    __builtin_amdgcn_s_setprio(0);

    // ---- p1: lgkm(0) | B2 (WAR: all waves' buf-d reads done) |
    //      stage A(t+2) into buf d | q1: m0-7 x n2-3 ----
    asm volatile("s_waitcnt lgkmcnt(0)" ::: "memory");
    __builtin_amdgcn_s_barrier();  // B2
    if (t + 2 < NT) STAGE_A(d, t + 2);
    __builtin_amdgcn_s_setprio(1);
#pragma unroll
    for (int m = 0; m < 8; ++m)
#pragma unroll
      for (int n = 2; n < 4; ++n) MFMA(acc[m][n], a[m], b[n]);
    __builtin_amdgcn_s_setprio(0);

    // ---- tile end: vmcnt | B3 (RAW: A(t+1),B(t+1) landed chip-wide) ----
    if (t < NT - 2) {
      asm volatile("s_waitcnt vmcnt(4)" ::: "memory");  // keep A(t+2) flying
    } else {
      asm volatile("s_waitcnt vmcnt(0)" ::: "memory");  // tail drain
    }
    __builtin_amdgcn_s_barrier();  // B3
  }

  // --- epilogue: i32->f32, per-wave LDS transpose, coalesced f32x4 stores ---
  // C/D 16x16: col = lane&15 (=fr), row = g*4 + reg.
  // y = sx[row]*( s[col]*G + s[col]*(128-zp[col])*rq[row] ) + bias[col]
  {
    const int wrow0 = row0 + wm * 128;
    const int wcol0 = col0 + wn * 64;
    float* eps = (float*)lds + wave * 2176;  // 32x68 f32, wave-private
    const f32x4 p4 = *(const f32x4*)(scale + wcol0 + 4 * fr);
    const f32x4 z4 = *(const f32x4*)(zp + wcol0 + 4 * fr);
    const f32x4 b4 = *(const f32x4*)(bias + wcol0 + 4 * fr);
    const f32x4 w04 = p4 * (128.0f - z4);
#pragma unroll
    for (int c = 0; c < 4; ++c) {
#pragma unroll
      for (int mm = 0; mm < 2; ++mm)
#pragma unroll
        for (int n = 0; n < 4; ++n)
#pragma unroll
          for (int q = 0; q < 4; ++q)
            eps[(mm * 16 + g * 4 + q) * 68 + n * 16 + fr] =
                (float)acc[2 * c + mm][n][q];
      asm volatile("s_waitcnt lgkmcnt(0)" ::: "memory");
#pragma unroll
      for (int j = 0; j < 8; ++j) {
        const int rl = j * 4 + g;                 // 0..31
        const int grow = wrow0 + c * 32 + rl;
        const f32x4 v = *(const f32x4*)(eps + rl * 68 + 4 * fr);
        const float sxr = sx[grow];
        const float rqr = rq[grow];
        const f32x4 o4 = sxr * (p4 * v + w04 * rqr) + b4;
        *(f32x4*)(out + (size_t)grow * NDIM + wcol0 + 4 * fr) = o4;
      }
      asm volatile("s_waitcnt lgkmcnt(0)" ::: "memory");  // WAR before reuse
    }
  }
#undef STAGE_A
#undef STAGE_B
#undef LDA
#undef LDB
#undef MFMA
}

// --- launch ------------------------------------------------------------------

extern "C" void kernel_launch(void* const* d_in, const int* in_sizes, int n_in,
                              void* d_out, int out_size, void* d_ws,
                              size_t ws_size, hipStream_t stream) {
  const float* x = (const float*)d_in[0];
  const int* wq = (const int*)d_in[1];
  const float* scale = (const float*)d_in[2];
  const float* zp = (const float*)d_in[3];
  const float* bias = (const float*)d_in[4];
  float* out = (float*)d_out;

  // workspace: xq 32 MiB | wq8 16 MiB | sx 32 KiB | rq 32 KiB
  char* ws = (char*)d_ws;
  s8* xq = (s8*)ws;
  s8* wq8 = (s8*)(ws + (size_t)M_TOK * KDIM);
  float* sx = (float*)(ws + (size_t)M_TOK * KDIM + (size_t)NDIM * KDIM);
  float* rq = (float*)(ws + (size_t)M_TOK * KDIM + (size_t)NDIM * KDIM +
                       (size_t)M_TOK * 4);

  (void)hipFuncSetAttribute((const void*)qlin_gemm_kernel,
                            hipFuncAttributeMaxDynamicSharedMemorySize,
                            49152);

  convert_x_kernel<<<M_TOK, 256, 0, stream>>>(x, xq, sx, rq);
  convert_w_kernel<<<(NDIM * (size_t)KDIM) / (256 * 16), 256, 0, stream>>>(
      wq, wq8);

  qlin_gemm_kernel<<<dim3((M_TOK / 256) * (NDIM / 128)), dim3(256), 49152,
                     stream>>>((const u8*)xq, (const u8*)wq8, sx, rq, scale,
                               zp, bias, out);
}

// Round 14
// 169.653 us; speedup vs baseline: 1.4009x; 1.4009x over previous
//
#include <hip/hip_runtime.h>

// ---------------------------------------------------------------------------
// QuantizedLinear: y = x @ ((q - zp)*s)^T + bias    — INT8 MFMA path.
// Per-row x quant: s_x[m] = max|x[m,:]|/127, xq = rint(x/s_x)  (s8)
// Weight: qs8 = q - 128 (exact).  EXACT given quantized x:
//   y[m,o] = s_x[m]*s[o]*( G8[m,o] + (128-zp[o])*rq[m] ) + bias[o]
// Round 14 = R10 verbatim (best measured: GEMM 120.7 µs, total 169.9 µs).
// R11 (32x32 MFMA): -10% — broke swizzle, 13.1M bank conflicts.
// R12 (BN=128 + 4-slot XOR): -23% — 16-bank row stride = 4-way conflict.
// R13 (fragment-order staging): -77% — uncoalesced GLDS + 1.75x FETCH.
// Structure: 256x256 i8 GEMM, BK=128, 8 waves (2Mx4N), 128 KiB dbuf LDS,
// 2 barriers/tile (B2 WAR + B3 RAW; audit in R10), counted lgkm 4/8/0,
// vmcnt 4 steady / 0 tail, T5 setprio, T1 XCD swizzle, slot^(row&7) LDS
// swizzle (conflict-free, verified R7 PMC).
// ---------------------------------------------------------------------------

typedef unsigned char u8;
typedef signed char s8;
typedef __attribute__((ext_vector_type(4))) int i32x4;
typedef __attribute__((ext_vector_type(4))) float f32x4;

#define M_TOK 8192
#define KDIM 4096
#define NDIM 4096
#define NT (KDIM / 128)  // 32 K-tiles of 128 i8

// --- helpers ---------------------------------------------------------------

__device__ __forceinline__ int pack4(int a, int b, int c, int d) {
  return (a & 255) | ((b & 255) << 8) | ((c & 255) << 16) |
         (int)(((unsigned)(d & 255)) << 24);
}

#define GLDS(gptr, lptr)                                                      \
  __builtin_amdgcn_global_load_lds(                                          \
      (const __attribute__((address_space(1))) void*)(gptr),                 \
      (__attribute__((address_space(3))) void*)(lptr), 16, 0, 0)

// --- kernel 1: x f32 -> s8 per-row quant, fused row max + row sum ----------

__global__ __launch_bounds__(256) void convert_x_kernel(
    const float* __restrict__ x, s8* __restrict__ xq,
    float* __restrict__ sx, float* __restrict__ rq) {
  const int row = blockIdx.x;
  const int tid = threadIdx.x;
  const float* xr = x + (size_t)row * KDIM + tid * 16;
  float4 v[4];
#pragma unroll
  for (int i = 0; i < 4; ++i) v[i] = ((const float4*)xr)[i];

  float mx = 0.f;
#pragma unroll
  for (int i = 0; i < 4; ++i) {
    mx = fmaxf(mx, fabsf(v[i].x)); mx = fmaxf(mx, fabsf(v[i].y));
    mx = fmaxf(mx, fabsf(v[i].z)); mx = fmaxf(mx, fabsf(v[i].w));
  }
#pragma unroll
  for (int off = 32; off > 0; off >>= 1)
    mx = fmaxf(mx, __shfl_down(mx, off, 64));
  __shared__ float redf[4];
  __shared__ float bmax;
  if ((tid & 63) == 0) redf[tid >> 6] = mx;
  __syncthreads();
  if (tid == 0)
    bmax = fmaxf(fmaxf(redf[0], redf[1]), fmaxf(redf[2], redf[3]));
  __syncthreads();
  const float maxv = bmax;
  const float inv = 127.0f / fmaxf(maxv, 1e-30f);

  int q[16];
  int ssum = 0;
#pragma unroll
  for (int i = 0; i < 4; ++i) {
    q[i * 4 + 0] = (int)rintf(v[i].x * inv);
    q[i * 4 + 1] = (int)rintf(v[i].y * inv);
    q[i * 4 + 2] = (int)rintf(v[i].z * inv);
    q[i * 4 + 3] = (int)rintf(v[i].w * inv);
  }
#pragma unroll
  for (int i = 0; i < 16; ++i) ssum += q[i];

  int4 o;
  o.x = pack4(q[0], q[1], q[2], q[3]);
  o.y = pack4(q[4], q[5], q[6], q[7]);
  o.z = pack4(q[8], q[9], q[10], q[11]);
  o.w = pack4(q[12], q[13], q[14], q[15]);
  *(int4*)(xq + (size_t)row * KDIM + tid * 16) = o;

#pragma unroll
  for (int off = 32; off > 0; off >>= 1) ssum += __shfl_down(ssum, off, 64);
  __shared__ int redi[4];
  if ((tid & 63) == 0) redi[tid >> 6] = ssum;
  __syncthreads();
  if (tid == 0) {
    sx[row] = maxv * (1.0f / 127.0f);
    rq[row] = (float)(redi[0] + redi[1] + redi[2] + redi[3]);  // < 2^24 exact
  }
}

// --- kernel 2: w int32 -> s8 (q - 128, exact) --------------------------------

__global__ __launch_bounds__(256) void convert_w_kernel(
    const int* __restrict__ wq, s8* __restrict__ wb) {
  const size_t idx = (size_t)blockIdx.x * 256 + threadIdx.x;  // 16 elems each
  const int4* src = (const int4*)wq + idx * 4;
  const int4 a = src[0], b = src[1], c = src[2], d = src[3];
  int4 o;
  o.x = pack4(a.x - 128, a.y - 128, a.z - 128, a.w - 128);
  o.y = pack4(b.x - 128, b.y - 128, b.z - 128, b.w - 128);
  o.z = pack4(c.x - 128, c.y - 128, c.z - 128, c.w - 128);
  o.w = pack4(d.x - 128, d.y - 128, d.z - 128, d.w - 128);
  ((int4*)wb)[idx] = o;
}

// --- kernel 3: 256x256 i8 GEMM, BK=128, 2 barriers/tile ---------------------

__global__ __launch_bounds__(512, 2) void qlin_gemm_kernel(
    const u8* __restrict__ A,         // [M][K] s8 bits
    const u8* __restrict__ B,         // [N][K] s8 bits
    const float* __restrict__ sx,     // [M]
    const float* __restrict__ rq,     // [M]
    const float* __restrict__ scale,  // [N]
    const float* __restrict__ zp,     // [N]
    const float* __restrict__ bias,   // [N]
    float* __restrict__ out) {        // [M][N]
  extern __shared__ u8 lds[];
  u8* Al = lds;           // [2][256][128]
  u8* Bl = lds + 65536;   // [2][256][128]

  const int tid = threadIdx.x;
  const int lane = tid & 63;
  const int wave = tid >> 6;
  const int wm = wave >> 2;  // 0..1
  const int wn = wave & 3;   // 0..3

  // T1: bijective XCD swizzle (512 wgs, 512%8==0)
  const int bid = blockIdx.x;
  const int swz = (bid & 7) * 64 + (bid >> 3);
  const int bm = swz >> 4;   // 0..31
  const int bn = swz & 15;   // 0..15
  const int row0 = bm * 256, col0 = bn * 256;

  // staging: thread t -> row t>>3, slot (t&7)^(row&7) pre-swizzled source.
  const int sr = tid >> 3;
  const int ss = (tid & 7) ^ (sr & 7);
  const u8* Ags = A + (size_t)(row0 + sr) * KDIM + ss * 16;
  const u8* Bgs = B + (size_t)(col0 + sr) * KDIM + ss * 16;
  u8* Ald = Al + wave * 1024;
  u8* Bld = Bl + wave * 1024;

#define STAGE_A(d, tau, h)                                                    \
  do {                                                                        \
    const u8* _g = Ags + (size_t)(h) * 128 * KDIM + (tau) * 128;             \
    u8* _l = Ald + (d) * 32768 + (h) * 16384;                                \
    GLDS(_g, _l);                                                            \
    GLDS(_g + (size_t)64 * KDIM, _l + 8192);                                 \
  } while (0)

#define STAGE_B(d, tau, h)                                                    \
  do {                                                                        \
    const u8* _g = Bgs + (size_t)(h) * 128 * KDIM + (tau) * 128;             \
    u8* _l = Bld + (d) * 32768 + (h) * 16384;                                \
    GLDS(_g, _l);                                                            \
    GLDS(_g + (size_t)64 * KDIM, _l + 8192);                                 \
  } while (0)

  // fragment reads (XOR-swizzled, verified R7)
  const int r = lane & 15;
  const int g = lane >> 4;
  const int swzx = (lane & 7) << 4;
  const int ce0 = (g * 16) ^ swzx;        // bytes, ks=0
  const int ce1 = (64 + g * 16) ^ swzx;   // bytes, ks=1
  const u8* Ar = Al + (wm * 128 + r) * 128;
  const u8* Br = Bl + (wn * 64 + r) * 128;

#define LDA(base, m, ks) \
  (*(const i32x4*)((base) + (m) * 2048 + ((ks) ? ce1 : ce0)))
#define LDB(base, n, ks) \
  (*(const i32x4*)((base) + (n) * 2048 + ((ks) ? ce1 : ce0)))
#define MFMA(d, va, vb) \
  d = __builtin_amdgcn_mfma_i32_16x16x64_i8(va, vb, d, 0, 0, 0)

  i32x4 acc[8][4] = {};
  i32x4 a[8][2], b[4][2];

  // prologue: A(0), B(0), A(1) = 12 GLDS; vmcnt(4) -> A(0),B(0) landed.
  STAGE_A(0, 0, 0); STAGE_A(0, 0, 1);
  STAGE_B(0, 0, 0); STAGE_B(0, 0, 1);
  STAGE_A(1, 1, 0); STAGE_A(1, 1, 1);
  asm volatile("s_waitcnt vmcnt(4)" ::: "memory");
  __builtin_amdgcn_s_barrier();
#pragma unroll
  for (int m = 0; m < 4; ++m) {
    a[m][0] = LDA(Ar, m, 0); a[m][1] = LDA(Ar, m, 1);
  }

  for (int t = 0; t < NT; ++t) {
    const int d = t & 1;
    const u8* Ard = Ar + d * 32768;
    const u8* Brd = Br + d * 32768;
    const u8* ArdN = Ar + (d ^ 1) * 32768;

    // ---- p0: read b0-1 | fence | b2-3 | stage B(t+1)h0 | lgkm(4) | q0 ----
    // (no barrier: per-wave lgkm count; region hazards covered by B3(t-1))
#pragma unroll
    for (int n = 0; n < 2; ++n) {
      b[n][0] = LDB(Brd, n, 0); b[n][1] = LDB(Brd, n, 1);
    }
    asm volatile("" ::: "memory");  // pin b0-1 before b2-3 (counted lgkm)
#pragma unroll
    for (int n = 2; n < 4; ++n) {
      b[n][0] = LDB(Brd, n, 0); b[n][1] = LDB(Brd, n, 1);
    }
    if (t + 1 < NT) STAGE_B(d ^ 1, t + 1, 0);
    asm volatile("s_waitcnt lgkmcnt(4)" ::: "memory");  // a0-3 + b0-1 ready
    __builtin_amdgcn_s_setprio(1);
#pragma unroll
    for (int ks = 0; ks < 2; ++ks)
#pragma unroll
      for (int m = 0; m < 4; ++m)
#pragma unroll
        for (int n = 0; n < 2; ++n) MFMA(acc[m][n], a[m][ks], b[n][ks]);
    __builtin_amdgcn_s_setprio(0);

    // ---- p1: read a4-7 | stage B(t+1)h1 | lgkm(8) | q1 ----
#pragma unroll
    for (int m = 4; m < 8; ++m) {
      a[m][0] = LDA(Ard, m, 0); a[m][1] = LDA(Ard, m, 1);
    }
    if (t + 1 < NT) STAGE_B(d ^ 1, t + 1, 1);
    asm volatile("s_waitcnt lgkmcnt(8)" ::: "memory");  // b2-3 ready
    __builtin_amdgcn_s_setprio(1);
#pragma unroll
    for (int ks = 0; ks < 2; ++ks)
#pragma unroll
      for (int m = 0; m < 4; ++m)
#pragma unroll
        for (int n = 2; n < 4; ++n) MFMA(acc[m][n], a[m][ks], b[n][ks]);
    __builtin_amdgcn_s_setprio(0);

    // ---- p2: lgkm(0) | B2 [all waves' buf-d A reads done] | stage A(t+2)
    //      | q2 ----
    asm volatile("s_waitcnt lgkmcnt(0)" ::: "memory");
    __builtin_amdgcn_s_barrier();  // B2: WAR fence for Al buf d
    if (t + 2 < NT) { STAGE_A(d, t + 2, 0); STAGE_A(d, t + 2, 1); }
    __builtin_amdgcn_s_setprio(1);
#pragma unroll
    for (int ks = 0; ks < 2; ++ks)
#pragma unroll
      for (int m = 4; m < 8; ++m)
#pragma unroll
        for (int n = 0; n < 2; ++n) MFMA(acc[m][n], a[m][ks], b[n][ks]);
    __builtin_amdgcn_s_setprio(0);

    // ---- p3: vmcnt | B3 [staged tiles landed chip-wide] | read next a0-3
    //      | q3 ----
    if (t < NT - 2) {
      asm volatile("s_waitcnt vmcnt(4)" ::: "memory");  // A(t+1),B(t+1) landed
    } else {
      asm volatile("s_waitcnt vmcnt(0)" ::: "memory");  // tail drain
    }
    __builtin_amdgcn_s_barrier();  // B3: RAW fence for staged data
    if (t + 1 < NT) {
#pragma unroll
      for (int m = 0; m < 4; ++m) {
        a[m][0] = LDA(ArdN, m, 0); a[m][1] = LDA(ArdN, m, 1);
      }
    }
    __builtin_amdgcn_s_setprio(1);
#pragma unroll
    for (int ks = 0; ks < 2; ++ks)
#pragma unroll
      for (int m = 4; m < 8; ++m)
#pragma unroll
        for (int n = 2; n < 4; ++n) MFMA(acc[m][n], a[m][ks], b[n][ks]);
    __builtin_amdgcn_s_setprio(0);
  }

  // --- epilogue: i32->f32, per-wave LDS transpose, coalesced f32x4 stores ---
  // y = sx[row]*( s[col]*G + s[col]*(128-zp[col])*rq[row] ) + bias[col]
  {
    const int wrow0 = row0 + wm * 128;
    const int wcol0 = col0 + wn * 64;
    float* eps = (float*)lds + wave * 2176;  // 32x68 f32, wave-private
    const f32x4 p4 = *(const f32x4*)(scale + wcol0 + 4 * r);
    const f32x4 z4 = *(const f32x4*)(zp + wcol0 + 4 * r);
    const f32x4 b4 = *(const f32x4*)(bias + wcol0 + 4 * r);
    const f32x4 w04 = p4 * (128.0f - z4);
#pragma unroll
    for (int c = 0; c < 4; ++c) {
#pragma unroll
      for (int mm = 0; mm < 2; ++mm)
#pragma unroll
        for (int n = 0; n < 4; ++n)
#pragma unroll
          for (int q = 0; q < 4; ++q)
            eps[(mm * 16 + g * 4 + q) * 68 + n * 16 + r] =
                (float)acc[2 * c + mm][n][q];
      asm volatile("s_waitcnt lgkmcnt(0)" ::: "memory");
#pragma unroll
      for (int j = 0; j < 8; ++j) {
        const int rl = j * 4 + g;                 // 0..31
        const int grow = wrow0 + c * 32 + rl;
        const f32x4 v = *(const f32x4*)(eps + rl * 68 + 4 * r);
        const float sxr = sx[grow];
        const float rqr = rq[grow];
        const f32x4 o4 = sxr * (p4 * v + w04 * rqr) + b4;
        *(f32x4*)(out + (size_t)grow * NDIM + wcol0 + 4 * r) = o4;
      }
      asm volatile("s_waitcnt lgkmcnt(0)" ::: "memory");  // WAR before reuse
    }
  }
#undef STAGE_A
#undef STAGE_B
#undef LDA
#undef LDB
#undef MFMA
}

// --- launch ------------------------------------------------------------------

extern "C" void kernel_launch(void* const* d_in, const int* in_sizes, int n_in,
                              void* d_out, int out_size, void* d_ws,
                              size_t ws_size, hipStream_t stream) {
  const float* x = (const float*)d_in[0];
  const int* wq = (const int*)d_in[1];
  const float* scale = (const float*)d_in[2];
  const float* zp = (const float*)d_in[3];
  const float* bias = (const float*)d_in[4];
  float* out = (float*)d_out;

  // workspace: xq 32 MiB | wq8 16 MiB | sx 32 KiB | rq 32 KiB
  char* ws = (char*)d_ws;
  s8* xq = (s8*)ws;
  s8* wq8 = (s8*)(ws + (size_t)M_TOK * KDIM);
  float* sx = (float*)(ws + (size_t)M_TOK * KDIM + (size_t)NDIM * KDIM);
  float* rq = (float*)(ws + (size_t)M_TOK * KDIM + (size_t)NDIM * KDIM +
                       (size_t)M_TOK * 4);

  (void)hipFuncSetAttribute((const void*)qlin_gemm_kernel,
                            hipFuncAttributeMaxDynamicSharedMemorySize,
                            131072);

  convert_x_kernel<<<M_TOK, 256, 0, stream>>>(x, xq, sx, rq);
  convert_w_kernel<<<(NDIM * (size_t)KDIM) / (256 * 16), 256, 0, stream>>>(
      wq, wq8);

  qlin_gemm_kernel<<<dim3((M_TOK / 256) * (NDIM / 256)), dim3(512), 131072,
                     stream>>>((const u8*)xq, (const u8*)wq8, sx, rq, scale,
                               zp, bias, out);
}